// Round 6
// baseline (218.935 us; speedup 1.0000x reference)
//
#include <hip/hip_runtime.h>
#include <cstdint>
#include <cstddef>

#define TPB 256

typedef __bf16 bf16x8 __attribute__((ext_vector_type(8)));
typedef float f32x4 __attribute__((ext_vector_type(4)));

union FragU { ushort u[8]; uint4 q; bf16x8 v; };

__device__ __forceinline__ ushort f2bf(float f)
{
    union { float f; uint32_t u; } v; v.f = f;
    uint32_t r = v.u + 0x7FFFu + ((v.u >> 16) & 1u);   // RNE
    return (ushort)(r >> 16);
}

// prep: fc (blocks 0..511) + zero cnt (blocks 512..595)
__global__ __launch_bounds__(TPB) void k_prep(
    const float* __restrict__ lat, const float* __restrict__ W,
    const float* __restrict__ bias, float* __restrict__ out,
    int* __restrict__ cnt)
{
    int bx = blockIdx.x;
    if (bx < 512) {
        int tid = bx * TPB + threadIdx.x;   // 131072
        int c = tid & 63;
        int b = (tid >> 6) & 7;
        int n = tid >> 9;
        int j = n * 64 + c;
        float acc = bias[j];
        const float* lb = lat + b * 64;
#pragma unroll 16
        for (int l = 0; l < 64; ++l)
            acc = fmaf(lb[l], W[l * 16384 + j], acc);
        out[tid] = acc;
    } else {
        int tid = (bx - 512) * TPB + threadIdx.x;
        if (tid < 21504) cnt[tid] = 0;
    }
}

// Fused fold: blocks [0,GF) write F=feat@W in MFMA B-frag order (bf16);
// blocks [GF,..) write UbW = Ub@W (row-major fp32).
template<int CI, int CO, int KF, int GF, int NBUB>
__global__ __launch_bounds__(TPB) void k_foldB(
    const float* __restrict__ X, const float* __restrict__ W,
    const float* __restrict__ Ub,
    ushort* __restrict__ Fq, float* __restrict__ UbW)
{
    int bx = blockIdx.x;
    if (bx < GF) {
        int tid = bx * TPB + threadIdx.x;
        int co = tid % CO;
        int nb = tid / CO;
        const float* x = X + (size_t)nb * CI;
        float acc = 0.f;
#pragma unroll
        for (int ci = 0; ci < CI; ++ci)
            acc = fmaf(x[ci], W[ci * CO + co], acc);
        int n = nb >> 3, bb = nb & 7;
        int col = bb * CO + co;
        int ks = n >> 5, r = n & 31, kq = r >> 3, j = r & 7;
        int ct = col >> 4, cl = col & 15;
        size_t idx = ((((size_t)ct * (KF / 32) + ks) * 4 + kq) * 16 + cl) * 8 + j;
        Fq[idx] = f2bf(acc);
    } else {
        int tid = (bx - GF) * TPB + threadIdx.x;
        if (tid >= NBUB * CO) return;
        int co = tid % CO;
        int row = tid / CO;
        const float* x = Ub + (size_t)row * CI;
        float acc = 0.f;
#pragma unroll
        for (int ci = 0; ci < CI; ++ci)
            acc = fmaf(x[ci], W[ci * CO + co], acc);
        UbW[tid] = acc;
    }
}

// Layer-2 fold: 32-col padded frag (cols 24..31 zero) + UbW.
__global__ __launch_bounds__(TPB) void k_foldB2(
    const float* __restrict__ X, const float* __restrict__ W,
    const float* __restrict__ Ub,
    ushort* __restrict__ Fq, float* __restrict__ UbW)
{
    int bx = blockIdx.x;
    if (bx < 512) {
        int tid = bx * TPB + threadIdx.x;    // 131072 = 4096 n x 32 colp
        int colp = tid & 31;
        int n = tid >> 5;
        float acc = 0.f;
        if (colp < 24) {
            int b = colp / 3, co = colp - b * 3;
            const float* x = X + (size_t)(n * 8 + b) * 32;
#pragma unroll
            for (int ci = 0; ci < 32; ++ci)
                acc = fmaf(x[ci], W[ci * 3 + co], acc);
        }
        int ks = n >> 5, r = n & 31, kq = r >> 3, j = r & 7;
        int ct = colp >> 4, cl = colp & 15;
        size_t idx = ((((size_t)ct * (4096 / 32) + ks) * 4 + kq) * 16 + cl) * 8 + j;
        Fq[idx] = f2bf(acc);
    } else {
        int tid = (bx - 512) * TPB + threadIdx.x;
        if (tid >= 49152) return;
        int co = tid % 3;
        int row = tid / 3;
        const float* x = Ub + (size_t)row * 32;
        float acc = 0.f;
#pragma unroll
        for (int ci = 0; ci < 32; ++ci)
            acc = fmaf(x[ci], W[ci * 3 + co], acc);
        UbW[tid] = acc;
    }
}

// ---------------- LDS-free MFMA GEMM ----------------
#define LOAD_STEP(S, t)                                                     \
    if ((t) < KS) {                                                         \
        _Pragma("unroll")                                                   \
        for (int rf = 0; rf < RF; ++rf) {                                   \
            a[S][rf][0] = *reinterpret_cast<const float4*>(Ap[rf] + (t) * 32);     \
            a[S][rf][1] = *reinterpret_cast<const float4*>(Ap[rf] + (t) * 32 + 4); \
        }                                                                   \
        _Pragma("unroll")                                                   \
        for (int cf = 0; cf < 2; ++cf)                                      \
            b[S][cf] = *reinterpret_cast<const uint4*>(Bp[cf] + (t) * 512); \
    }

#define COMP_STEP(S)                                                        \
    {                                                                       \
        _Pragma("unroll")                                                   \
        for (int rf = 0; rf < RF; ++rf) {                                   \
            const float* fa = reinterpret_cast<const float*>(&a[S][rf][0]); \
            bf16x8 av;                                                      \
            _Pragma("unroll")                                               \
            for (int j = 0; j < 8; ++j) av[j] = (__bf16)fa[j];              \
            _Pragma("unroll")                                               \
            for (int cf = 0; cf < 2; ++cf) {                                \
                FragU bfr; bfr.q = b[S][cf];                                \
                acc[rf][cf] = __builtin_amdgcn_mfma_f32_16x16x32_bf16(      \
                    av, bfr.v, acc[rf][cf], 0, 0, 0);                       \
            }                                                               \
        }                                                                   \
    }

template<int K, int NTOT, int CO, int RF, int KSPLIT, bool SPLIT>
__global__ __launch_bounds__(TPB) void k_gemm_mfma(
    const float* __restrict__ U, const ushort* __restrict__ Fq,
    const float* __restrict__ UbW, float* __restrict__ up)
{
    constexpr int KCH = K / KSPLIT;
    constexpr int KS = KCH / 32;
    static_assert(KS % 2 == 0, "even k-steps");

    const int lane = threadIdx.x & 63;
    const int w = threadIdx.x >> 6;
    const int rowbase = (blockIdx.x * 4 + w) * (RF * 16);
    const int jt = blockIdx.y;
    const int kz = blockIdx.z;
    const int kq = lane >> 4;
    const int m = lane & 15;
    const int M = gridDim.x * (4 * RF * 16);

    const float* Ap[RF];
#pragma unroll
    for (int rf = 0; rf < RF; ++rf)
        Ap[rf] = U + (size_t)(rowbase + rf * 16 + m) * K + kz * KCH + kq * 8;

    const ushort* Bp[2];
#pragma unroll
    for (int cf = 0; cf < 2; ++cf)
        Bp[cf] = Fq + ((size_t)((jt * 2 + cf) * (K / 32) + (kz * KCH) / 32) * 64 + lane) * 8;

    f32x4 acc[RF][2];
#pragma unroll
    for (int rf = 0; rf < RF; ++rf)
#pragma unroll
        for (int cf = 0; cf < 2; ++cf)
            acc[rf][cf] = (f32x4){0.f, 0.f, 0.f, 0.f};

    float4 a[2][RF][2];
    uint4  b[2][2];

    LOAD_STEP(0, 0)
    for (int t = 0; t < KS; t += 2) {
        LOAD_STEP(1, t + 1)
        COMP_STEP(0)
        LOAD_STEP(0, t + 2)
        COMP_STEP(1)
    }

#pragma unroll
    for (int rf = 0; rf < RF; ++rf)
#pragma unroll
        for (int cf = 0; cf < 2; ++cf)
#pragma unroll
            for (int r = 0; r < 4; ++r) {
                int row = rowbase + rf * 16 + kq * 4 + r;
                int col = jt * 32 + cf * 16 + m;
                if (col < NTOT) {
                    float v = acc[rf][cf][r];
                    if (!SPLIT) {
                        up[(size_t)row * NTOT + col] =
                            v + UbW[(size_t)row * CO + col % CO];
                    } else {
                        if (kz == 0) v += UbW[(size_t)row * CO + col % CO];
                        up[((size_t)kz * M + row) * NTOT + col] = v;
                    }
                }
            }
}

// ---------------- CSR build ----------------
__global__ __launch_bounds__(TPB) void k_hist(
    const int* __restrict__ r0, const int* __restrict__ r1,
    const int* __restrict__ r2, int* __restrict__ cnt)
{
    int e = blockIdx.x * TPB + threadIdx.x;      // 344064
    if (e < 16384)        atomicAdd(&cnt[r0[e]], 1);
    else if (e < 81920)   atomicAdd(&cnt[1024 + r1[e - 16384]], 1);
    else if (e < 344064)  atomicAdd(&cnt[5120 + r2[e - 81920]], 1);
}

__global__ __launch_bounds__(1024) void k_scan(
    const int* __restrict__ cnt, int* __restrict__ offs, int* __restrict__ cur)
{
    constexpr int N = 21504, PER = 21;
    __shared__ int wsum[16];
    int tid = threadIdx.x;
    int base = tid * PER;
    int c[PER];
    int s = 0;
#pragma unroll
    for (int i = 0; i < PER; ++i) { c[i] = s; s += cnt[base + i]; }
    int lane = tid & 63, w = tid >> 6;
    int v = s;
#pragma unroll
    for (int d = 1; d < 64; d <<= 1) {
        int t = __shfl_up(v, d);
        if (lane >= d) v += t;
    }
    if (lane == 63) wsum[w] = v;
    __syncthreads();
    int woff = 0;
    for (int i = 0; i < w; ++i) woff += wsum[i];
    int excl = woff + v - s;
#pragma unroll
    for (int i = 0; i < PER; ++i) {
        int o = excl + c[i];
        offs[base + i] = o;
        cur[base + i] = o;
    }
    if (tid == 1023) offs[N] = excl + s;
}

__global__ __launch_bounds__(TPB) void k_fill(
    const int* __restrict__ r0, const int* __restrict__ c0, const float* __restrict__ v0,
    const int* __restrict__ r1, const int* __restrict__ c1, const float* __restrict__ v1,
    const int* __restrict__ r2, const int* __restrict__ c2, const float* __restrict__ v2,
    int* __restrict__ cur, int* __restrict__ ccol, float* __restrict__ cval)
{
    int e = blockIdx.x * TPB + threadIdx.x;
    int rbase, col; float val;
    if (e < 16384)       { rbase = 0;    col = c0[e];         val = v0[e];         rbase += r0[e]; }
    else if (e < 81920)  { int l = e - 16384; rbase = 1024;  col = c1[l]; val = v1[l]; rbase += r1[l]; }
    else if (e < 344064) { int l = e - 81920; rbase = 5120;  col = c2[l]; val = v2[l]; rbase += r2[l]; }
    else return;
    int pos = atomicAdd(&cur[rbase], 1);
    ccol[pos] = col;
    cval[pos] = val;
}

// ---------------- CSR gather (= A @ up), relu+bias folded ----------------
template<int BC, int CO, int NR, int RBASE, int NSPLIT, bool FINAL>
__global__ __launch_bounds__(TPB) void k_gather(
    const float* __restrict__ up, const int* __restrict__ offs,
    const int* __restrict__ ccol, const float* __restrict__ cval,
    const float* __restrict__ bias, float* __restrict__ out)
{
    constexpr int JQ = BC / 4;
    int tid = blockIdx.x * TPB + threadIdx.x;
    if (tid >= NR * JQ) return;
    int jq = tid % JQ;
    int r = tid / JQ;
    int p0 = offs[RBASE + r], p1 = offs[RBASE + r + 1];
    float4 acc = make_float4(0.f, 0.f, 0.f, 0.f);
    for (int p = p0; p < p1; ++p) {
        float v = cval[p];
        int c = ccol[p];
#pragma unroll
        for (int s = 0; s < NSPLIT; ++s) {
            float4 u = *reinterpret_cast<const float4*>(
                &up[((size_t)s * NR + c) * BC + jq * 4]);
            acc.x = fmaf(v, u.x, acc.x);
            acc.y = fmaf(v, u.y, acc.y);
            acc.z = fmaf(v, u.z, acc.z);
            acc.w = fmaf(v, u.w, acc.w);
        }
    }
    int col0 = jq * 4;
    if (!FINAL) {
        float4 o;
        o.x = fmaxf(acc.x + bias[(col0 + 0) % CO], 0.f);
        o.y = fmaxf(acc.y + bias[(col0 + 1) % CO], 0.f);
        o.z = fmaxf(acc.z + bias[(col0 + 2) % CO], 0.f);
        o.w = fmaxf(acc.w + bias[(col0 + 3) % CO], 0.f);
        *reinterpret_cast<float4*>(&out[(size_t)r * BC + col0]) = o;
    } else {
        float a[4] = {acc.x, acc.y, acc.z, acc.w};
#pragma unroll
        for (int e = 0; e < 4; ++e) {
            int col = col0 + e;
            int b = col / 3, j = col - b * 3;
            out[(size_t)b * 49152 + (size_t)r * 3 + j] = fmaxf(a[e] + bias[j], 0.f);
        }
    }
}

extern "C" void kernel_launch(void* const* d_in, const int* in_sizes, int n_in,
                              void* d_out, int out_size, void* d_ws, size_t ws_size,
                              hipStream_t stream)
{
    const float* lat   = (const float*)d_in[0];
    const float* fcW   = (const float*)d_in[1];
    const float* fcb   = (const float*)d_in[2];
    const float* U0    = (const float*)d_in[3];
    const float* Ub0   = (const float*)d_in[4];
    const float* W0    = (const float*)d_in[5];
    const float* b0    = (const float*)d_in[6];
    const float* vals0 = (const float*)d_in[7];
    const int*   rows0 = (const int*)d_in[8];
    const int*   cols0 = (const int*)d_in[9];
    const float* U1    = (const float*)d_in[10];
    const float* Ub1   = (const float*)d_in[11];
    const float* W1    = (const float*)d_in[12];
    const float* b1    = (const float*)d_in[13];
    const float* vals1 = (const float*)d_in[14];
    const int*   rows1 = (const int*)d_in[15];
    const int*   cols1 = (const int*)d_in[16];
    const float* U2    = (const float*)d_in[17];
    const float* Ub2   = (const float*)d_in[18];
    const float* W2    = (const float*)d_in[19];
    const float* b2    = (const float*)d_in[20];
    const float* vals2 = (const float*)d_in[21];
    const int*   rows2 = (const int*)d_in[22];
    const int*   cols2 = (const int*)d_in[23];

    float* ws = (float*)d_ws;
    float* fbuf0 = ws;                     // 131072
    float* fbuf1 = fbuf0 + 131072;         // 524288
    float* fbuf2 = fbuf1 + 524288;         // 1048576
    float* fWq   = fbuf2 + 1048576;        // 262144 (frag buffer storage)
    float* UbW   = fWq   + 262144;         // 131072
    float* up    = UbW   + 131072;         // 1572864 (4x layer-2 splits / reused)
    int*   offs  = (int*)(up + 1572864);   // 21760
    int*   cur   = offs + 21760;           // 21760
    int*   cnt   = cur + 21760;            // 21760
    int*   ccol  = cnt + 21760;            // 344064
    float* cval  = (float*)(ccol + 344064);// 344064

    ushort* Fq16 = (ushort*)fWq;
    float* out = (float*)d_out;

    // fc + cnt-zero
    hipLaunchKernelGGL(k_prep, dim3(596), dim3(TPB), 0, stream, lat, fcW, fcb, fbuf0, cnt);
    // CSR build
    hipLaunchKernelGGL(k_hist, dim3(1344), dim3(TPB), 0, stream, rows0, rows1, rows2, cnt);
    hipLaunchKernelGGL(k_scan, dim3(1), dim3(1024), 0, stream, cnt, offs, cur);
    hipLaunchKernelGGL(k_fill, dim3(1344), dim3(TPB), 0, stream,
                       rows0, cols0, vals0, rows1, cols1, vals1, rows2, cols2, vals2,
                       cur, ccol, cval);

    // ---- layer 0: M=1024 K=256 NTOT=512 CO=64 ----
    hipLaunchKernelGGL((k_foldB<64, 64, 256, 512, 1024>), dim3(768), dim3(TPB), 0, stream,
                       fbuf0, W0, Ub0, Fq16, UbW);
    hipLaunchKernelGGL((k_gemm_mfma<256, 512, 64, 1, 1, false>), dim3(16, 16, 1), dim3(TPB), 0, stream,
                       U0, Fq16, UbW, up);
    hipLaunchKernelGGL((k_gather<512, 64, 1024, 0, 1, false>), dim3(512), dim3(TPB), 0, stream,
                       up, offs, ccol, cval, b0, fbuf1);

    // ---- layer 1: M=4096 K=1024 NTOT=256 CO=32 ----
    hipLaunchKernelGGL((k_foldB<64, 32, 1024, 1024, 4096>), dim3(1536), dim3(TPB), 0, stream,
                       fbuf1, W1, Ub1, Fq16, UbW);
    hipLaunchKernelGGL((k_gemm_mfma<1024, 256, 32, 1, 1, false>), dim3(64, 8, 1), dim3(TPB), 0, stream,
                       U1, Fq16, UbW, up);
    hipLaunchKernelGGL((k_gather<256, 32, 4096, 1024, 1, false>), dim3(1024), dim3(TPB), 0, stream,
                       up, offs, ccol, cval, b1, fbuf2);

    // ---- layer 2: M=16384 K=4096 NTOT=24 (pad 32) CO=3, RF=2, KSPLIT=4 ----
    hipLaunchKernelGGL(k_foldB2, dim3(704), dim3(TPB), 0, stream, fbuf2, W2, Ub2, Fq16, UbW);
    hipLaunchKernelGGL((k_gemm_mfma<4096, 24, 3, 2, 4, true>), dim3(128, 1, 4), dim3(TPB), 0, stream,
                       U2, Fq16, UbW, up);
    hipLaunchKernelGGL((k_gather<24, 3, 16384, 5120, 4, true>), dim3(384), dim3(TPB), 0, stream,
                       up, offs, ccol, cval, b2, out);
}

// Round 7
// 198.231 us; speedup vs baseline: 1.1044x; 1.1044x over previous
//
#include <hip/hip_runtime.h>
#include <cstdint>
#include <cstddef>

#define TPB 256

typedef __bf16 bf16x8 __attribute__((ext_vector_type(8)));
typedef float f32x4 __attribute__((ext_vector_type(4)));

union FragU { ushort u[8]; uint4 q; bf16x8 v; };

__device__ __forceinline__ ushort f2bf(float f)
{
    union { float f; uint32_t u; } v; v.f = f;
    uint32_t r = v.u + 0x7FFFu + ((v.u >> 16) & 1u);   // RNE
    return (ushort)(r >> 16);
}

// prep: fc (blocks 0..511) + zero cnt (blocks 512..595)
__global__ __launch_bounds__(TPB) void k_prep(
    const float* __restrict__ lat, const float* __restrict__ W,
    const float* __restrict__ bias, float* __restrict__ out,
    int* __restrict__ cnt)
{
    int bx = blockIdx.x;
    if (bx < 512) {
        int tid = bx * TPB + threadIdx.x;   // 131072
        int c = tid & 63;
        int b = (tid >> 6) & 7;
        int n = tid >> 9;
        int j = n * 64 + c;
        float acc = bias[j];
        const float* lb = lat + b * 64;
#pragma unroll 16
        for (int l = 0; l < 64; ++l)
            acc = fmaf(lb[l], W[l * 16384 + j], acc);
        out[tid] = acc;
    } else {
        int tid = (bx - 512) * TPB + threadIdx.x;
        if (tid < 21504) cnt[tid] = 0;
    }
}

// Fused fold: blocks [0,GF) write F=feat@W in MFMA B-frag order (bf16);
// blocks [GF,..) write UbW = Ub@W (row-major fp32).
template<int CI, int CO, int KF, int GF, int NBUB>
__global__ __launch_bounds__(TPB) void k_foldB(
    const float* __restrict__ X, const float* __restrict__ W,
    const float* __restrict__ Ub,
    ushort* __restrict__ Fq, float* __restrict__ UbW)
{
    int bx = blockIdx.x;
    if (bx < GF) {
        int tid = bx * TPB + threadIdx.x;
        int co = tid % CO;
        int nb = tid / CO;
        const float* x = X + (size_t)nb * CI;
        float acc = 0.f;
#pragma unroll
        for (int ci = 0; ci < CI; ++ci)
            acc = fmaf(x[ci], W[ci * CO + co], acc);
        int n = nb >> 3, bb = nb & 7;
        int col = bb * CO + co;
        int ks = n >> 5, r = n & 31, kq = r >> 3, j = r & 7;
        int ct = col >> 4, cl = col & 15;
        size_t idx = ((((size_t)ct * (KF / 32) + ks) * 4 + kq) * 16 + cl) * 8 + j;
        Fq[idx] = f2bf(acc);
    } else {
        int tid = (bx - GF) * TPB + threadIdx.x;
        if (tid >= NBUB * CO) return;
        int co = tid % CO;
        int row = tid / CO;
        const float* x = Ub + (size_t)row * CI;
        float acc = 0.f;
#pragma unroll
        for (int ci = 0; ci < CI; ++ci)
            acc = fmaf(x[ci], W[ci * CO + co], acc);
        UbW[tid] = acc;
    }
}

// Layer-2 fold: 32-col padded frag (cols 24..31 zero) + UbW.
__global__ __launch_bounds__(TPB) void k_foldB2(
    const float* __restrict__ X, const float* __restrict__ W,
    const float* __restrict__ Ub,
    ushort* __restrict__ Fq, float* __restrict__ UbW)
{
    int bx = blockIdx.x;
    if (bx < 512) {
        int tid = bx * TPB + threadIdx.x;    // 131072 = 4096 n x 32 colp
        int colp = tid & 31;
        int n = tid >> 5;
        float acc = 0.f;
        if (colp < 24) {
            int b = colp / 3, co = colp - b * 3;
            const float* x = X + (size_t)(n * 8 + b) * 32;
#pragma unroll
            for (int ci = 0; ci < 32; ++ci)
                acc = fmaf(x[ci], W[ci * 3 + co], acc);
        }
        int ks = n >> 5, r = n & 31, kq = r >> 3, j = r & 7;
        int ct = colp >> 4, cl = colp & 15;
        size_t idx = ((((size_t)ct * (4096 / 32) + ks) * 4 + kq) * 16 + cl) * 8 + j;
        Fq[idx] = f2bf(acc);
    } else {
        int tid = (bx - 512) * TPB + threadIdx.x;
        if (tid >= 49152) return;
        int co = tid % 3;
        int row = tid / 3;
        const float* x = Ub + (size_t)row * 32;
        float acc = 0.f;
#pragma unroll
        for (int ci = 0; ci < 32; ++ci)
            acc = fmaf(x[ci], W[ci * 3 + co], acc);
        UbW[tid] = acc;
    }
}

// ---------------- LDS-free MFMA GEMM, intra-block wave K-split ----------------
// Block = 4 waves, all covering the same 16 rows x NC cols; wave w handles
// K-chunk [w*K/4, (w+1)*K/4). Register accumulate, then LDS cross-wave reduce.
// U is read exactly gridDim.y times total; no atomics, no split buffers.
template<int K, int NTOT, int CO, int CF>
__global__ __launch_bounds__(TPB) void k_gemm_ws(
    const float* __restrict__ U, const ushort* __restrict__ Fq,
    const float* __restrict__ UbW, float* __restrict__ up)
{
    constexpr int KCH = K / 4;         // per-wave K chunk
    constexpr int KS = KCH / 32;       // k-steps per wave
    constexpr int NC = CF * 16;        // cols per block
    static_assert(KS % 2 == 0, "even k-steps");

    __shared__ float red[4][NC * 16];

    const int tid = threadIdx.x;
    const int lane = tid & 63;
    const int w = tid >> 6;
    const int rowbase = blockIdx.x * 16;
    const int jt = blockIdx.y;
    const int kq = lane >> 4;
    const int m = lane & 15;

    const float* Ap = U + (size_t)(rowbase + m) * K + w * KCH + kq * 8;
    const ushort* Bp[CF];
#pragma unroll
    for (int cf = 0; cf < CF; ++cf)
        Bp[cf] = Fq + ((size_t)(jt * CF + cf) * (K / 32) + (size_t)w * KS) * 512
                 + lane * 8;

    f32x4 acc[CF];
#pragma unroll
    for (int cf = 0; cf < CF; ++cf)
        acc[cf] = (f32x4){0.f, 0.f, 0.f, 0.f};

    float4 a[2][2];
    uint4  b[2][CF];

#define LOAD_STEP(S, t)                                                     \
    if ((t) < KS) {                                                         \
        a[S][0] = *reinterpret_cast<const float4*>(Ap + (t) * 32);          \
        a[S][1] = *reinterpret_cast<const float4*>(Ap + (t) * 32 + 4);      \
        _Pragma("unroll")                                                   \
        for (int cf = 0; cf < CF; ++cf)                                     \
            b[S][cf] = *reinterpret_cast<const uint4*>(Bp[cf] + (t) * 512); \
    }

#define COMP_STEP(S)                                                        \
    {                                                                       \
        const float* fa = reinterpret_cast<const float*>(&a[S][0]);         \
        bf16x8 av;                                                          \
        _Pragma("unroll")                                                   \
        for (int j = 0; j < 8; ++j) av[j] = (__bf16)fa[j];                  \
        _Pragma("unroll")                                                   \
        for (int cf = 0; cf < CF; ++cf) {                                   \
            FragU bfr; bfr.q = b[S][cf];                                    \
            acc[cf] = __builtin_amdgcn_mfma_f32_16x16x32_bf16(              \
                av, bfr.v, acc[cf], 0, 0, 0);                               \
        }                                                                   \
    }

    LOAD_STEP(0, 0)
#pragma unroll
    for (int t = 0; t < KS; t += 2) {
        LOAD_STEP(1, t + 1)
        COMP_STEP(0)
        LOAD_STEP(0, t + 2)
        COMP_STEP(1)
    }
#undef LOAD_STEP
#undef COMP_STEP

    // write per-wave partials: red[w][col*16 + row], col=cf*16+m, row=kq*4+r
#pragma unroll
    for (int cf = 0; cf < CF; ++cf)
#pragma unroll
        for (int r = 0; r < 4; ++r)
            red[w][(cf * 16 + m) * 16 + kq * 4 + r] = acc[cf][r];
    __syncthreads();

#pragma unroll
    for (int e = tid; e < NC * 16; e += TPB) {
        int col = e >> 4, row = e & 15;
        float v = red[0][e] + red[1][e] + red[2][e] + red[3][e];
        int gcol = jt * NC + col;
        int grow = rowbase + row;
        if (gcol < NTOT)
            up[(size_t)grow * NTOT + gcol] =
                v + UbW[(size_t)grow * CO + gcol % CO];
    }
}

// ---------------- CSR build ----------------
__global__ __launch_bounds__(TPB) void k_hist(
    const int* __restrict__ r0, const int* __restrict__ r1,
    const int* __restrict__ r2, int* __restrict__ cnt)
{
    int e = blockIdx.x * TPB + threadIdx.x;      // 344064
    if (e < 16384)        atomicAdd(&cnt[r0[e]], 1);
    else if (e < 81920)   atomicAdd(&cnt[1024 + r1[e - 16384]], 1);
    else if (e < 344064)  atomicAdd(&cnt[5120 + r2[e - 81920]], 1);
}

__global__ __launch_bounds__(1024) void k_scan(
    const int* __restrict__ cnt, int* __restrict__ offs, int* __restrict__ cur)
{
    constexpr int N = 21504, PER = 21;
    __shared__ int wsum[16];
    int tid = threadIdx.x;
    int base = tid * PER;
    int c[PER];
    int s = 0;
#pragma unroll
    for (int i = 0; i < PER; ++i) { c[i] = s; s += cnt[base + i]; }
    int lane = tid & 63, w = tid >> 6;
    int v = s;
#pragma unroll
    for (int d = 1; d < 64; d <<= 1) {
        int t = __shfl_up(v, d);
        if (lane >= d) v += t;
    }
    if (lane == 63) wsum[w] = v;
    __syncthreads();
    int woff = 0;
    for (int i = 0; i < w; ++i) woff += wsum[i];
    int excl = woff + v - s;
#pragma unroll
    for (int i = 0; i < PER; ++i) {
        int o = excl + c[i];
        offs[base + i] = o;
        cur[base + i] = o;
    }
    if (tid == 1023) offs[N] = excl + s;
}

__global__ __launch_bounds__(TPB) void k_fill(
    const int* __restrict__ r0, const int* __restrict__ c0, const float* __restrict__ v0,
    const int* __restrict__ r1, const int* __restrict__ c1, const float* __restrict__ v1,
    const int* __restrict__ r2, const int* __restrict__ c2, const float* __restrict__ v2,
    int* __restrict__ cur, int* __restrict__ ccol, float* __restrict__ cval)
{
    int e = blockIdx.x * TPB + threadIdx.x;
    int rbase, col; float val;
    if (e < 16384)       { rbase = 0;    col = c0[e];         val = v0[e];         rbase += r0[e]; }
    else if (e < 81920)  { int l = e - 16384; rbase = 1024;  col = c1[l]; val = v1[l]; rbase += r1[l]; }
    else if (e < 344064) { int l = e - 81920; rbase = 5120;  col = c2[l]; val = v2[l]; rbase += r2[l]; }
    else return;
    int pos = atomicAdd(&cur[rbase], 1);
    ccol[pos] = col;
    cval[pos] = val;
}

// ---------------- CSR gather (= A @ up), relu+bias folded ----------------
template<int BC, int CO, int NR, int RBASE, bool FINAL>
__global__ __launch_bounds__(TPB) void k_gather(
    const float* __restrict__ up, const int* __restrict__ offs,
    const int* __restrict__ ccol, const float* __restrict__ cval,
    const float* __restrict__ bias, float* __restrict__ out)
{
    constexpr int JQ = BC / 4;
    int tid = blockIdx.x * TPB + threadIdx.x;
    if (tid >= NR * JQ) return;
    int jq = tid % JQ;
    int r = tid / JQ;
    int p0 = offs[RBASE + r], p1 = offs[RBASE + r + 1];
    float4 acc = make_float4(0.f, 0.f, 0.f, 0.f);
    for (int p = p0; p < p1; ++p) {
        float v = cval[p];
        int c = ccol[p];
        float4 u = *reinterpret_cast<const float4*>(&up[(size_t)c * BC + jq * 4]);
        acc.x = fmaf(v, u.x, acc.x);
        acc.y = fmaf(v, u.y, acc.y);
        acc.z = fmaf(v, u.z, acc.z);
        acc.w = fmaf(v, u.w, acc.w);
    }
    int col0 = jq * 4;
    if (!FINAL) {
        float4 o;
        o.x = fmaxf(acc.x + bias[(col0 + 0) % CO], 0.f);
        o.y = fmaxf(acc.y + bias[(col0 + 1) % CO], 0.f);
        o.z = fmaxf(acc.z + bias[(col0 + 2) % CO], 0.f);
        o.w = fmaxf(acc.w + bias[(col0 + 3) % CO], 0.f);
        *reinterpret_cast<float4*>(&out[(size_t)r * BC + col0]) = o;
    } else {
        float a[4] = {acc.x, acc.y, acc.z, acc.w};
#pragma unroll
        for (int e = 0; e < 4; ++e) {
            int col = col0 + e;
            int b = col / 3, j = col - b * 3;
            out[(size_t)b * 49152 + (size_t)r * 3 + j] = fmaxf(a[e] + bias[j], 0.f);
        }
    }
}

extern "C" void kernel_launch(void* const* d_in, const int* in_sizes, int n_in,
                              void* d_out, int out_size, void* d_ws, size_t ws_size,
                              hipStream_t stream)
{
    const float* lat   = (const float*)d_in[0];
    const float* fcW   = (const float*)d_in[1];
    const float* fcb   = (const float*)d_in[2];
    const float* U0    = (const float*)d_in[3];
    const float* Ub0   = (const float*)d_in[4];
    const float* W0    = (const float*)d_in[5];
    const float* b0    = (const float*)d_in[6];
    const float* vals0 = (const float*)d_in[7];
    const int*   rows0 = (const int*)d_in[8];
    const int*   cols0 = (const int*)d_in[9];
    const float* U1    = (const float*)d_in[10];
    const float* Ub1   = (const float*)d_in[11];
    const float* W1    = (const float*)d_in[12];
    const float* b1    = (const float*)d_in[13];
    const float* vals1 = (const float*)d_in[14];
    const int*   rows1 = (const int*)d_in[15];
    const int*   cols1 = (const int*)d_in[16];
    const float* U2    = (const float*)d_in[17];
    const float* Ub2   = (const float*)d_in[18];
    const float* W2    = (const float*)d_in[19];
    const float* b2    = (const float*)d_in[20];
    const float* vals2 = (const float*)d_in[21];
    const int*   rows2 = (const int*)d_in[22];
    const int*   cols2 = (const int*)d_in[23];

    float* ws = (float*)d_ws;
    float* fbuf0 = ws;                     // 131072
    float* fbuf1 = fbuf0 + 131072;         // 524288
    float* fbuf2 = fbuf1 + 524288;         // 1048576
    float* fWq   = fbuf2 + 1048576;        // 262144 (frag buffer storage)
    float* UbW   = fWq   + 262144;         // 131072
    float* up    = UbW   + 131072;         // 1048576
    int*   offs  = (int*)(up + 1048576);   // 21760
    int*   cur   = offs + 21760;           // 21760
    int*   cnt   = cur + 21760;            // 21760
    int*   ccol  = cnt + 21760;            // 344064
    float* cval  = (float*)(ccol + 344064);// 344064

    ushort* Fq16 = (ushort*)fWq;
    float* out = (float*)d_out;

    // fc + cnt-zero
    hipLaunchKernelGGL(k_prep, dim3(596), dim3(TPB), 0, stream, lat, fcW, fcb, fbuf0, cnt);
    // CSR build
    hipLaunchKernelGGL(k_hist, dim3(1344), dim3(TPB), 0, stream, rows0, rows1, rows2, cnt);
    hipLaunchKernelGGL(k_scan, dim3(1), dim3(1024), 0, stream, cnt, offs, cur);
    hipLaunchKernelGGL(k_fill, dim3(1344), dim3(TPB), 0, stream,
                       rows0, cols0, vals0, rows1, cols1, vals1, rows2, cols2, vals2,
                       cur, ccol, cval);

    // ---- layer 0: M=1024 K=256 NTOT=512 CO=64, CF=8 -> grid (64, 4) ----
    hipLaunchKernelGGL((k_foldB<64, 64, 256, 512, 1024>), dim3(768), dim3(TPB), 0, stream,
                       fbuf0, W0, Ub0, Fq16, UbW);
    hipLaunchKernelGGL((k_gemm_ws<256, 512, 64, 8>), dim3(64, 4), dim3(TPB), 0, stream,
                       U0, Fq16, UbW, up);
    hipLaunchKernelGGL((k_gather<512, 64, 1024, 0, false>), dim3(512), dim3(TPB), 0, stream,
                       up, offs, ccol, cval, b0, fbuf1);

    // ---- layer 1: M=4096 K=1024 NTOT=256 CO=32, CF=8 -> grid (256, 2) ----
    hipLaunchKernelGGL((k_foldB<64, 32, 1024, 1024, 4096>), dim3(1536), dim3(TPB), 0, stream,
                       fbuf1, W1, Ub1, Fq16, UbW);
    hipLaunchKernelGGL((k_gemm_ws<1024, 256, 32, 8>), dim3(256, 2), dim3(TPB), 0, stream,
                       U1, Fq16, UbW, up);
    hipLaunchKernelGGL((k_gather<256, 32, 4096, 1024, false>), dim3(1024), dim3(TPB), 0, stream,
                       up, offs, ccol, cval, b1, fbuf2);

    // ---- layer 2: M=16384 K=4096 NTOT=24 (pad 32) CO=3, CF=2 -> grid (1024, 1) ----
    hipLaunchKernelGGL(k_foldB2, dim3(704), dim3(TPB), 0, stream, fbuf2, W2, Ub2, Fq16, UbW);
    hipLaunchKernelGGL((k_gemm_ws<4096, 24, 3, 2>), dim3(1024, 1), dim3(TPB), 0, stream,
                       U2, Fq16, UbW, up);
    hipLaunchKernelGGL((k_gather<24, 3, 16384, 5120, true>), dim3(384), dim3(TPB), 0, stream,
                       up, offs, ccol, cval, b2, out);
}

// Round 8
// 192.453 us; speedup vs baseline: 1.1376x; 1.0300x over previous
//
#include <hip/hip_runtime.h>
#include <cstdint>
#include <cstddef>

#define TPB 256

typedef __bf16 bf16x8 __attribute__((ext_vector_type(8)));
typedef float f32x4 __attribute__((ext_vector_type(4)));

union FragU { ushort u[8]; uint4 q; bf16x8 v; };

__device__ __forceinline__ ushort f2bf(float f)
{
    union { float f; uint32_t u; } v; v.f = f;
    uint32_t r = v.u + 0x7FFFu + ((v.u >> 16) & 1u);   // RNE
    return (ushort)(r >> 16);
}

// prep: fc (blocks 0..511) + zero cnt (blocks 512..595)
__global__ __launch_bounds__(TPB) void k_prep(
    const float* __restrict__ lat, const float* __restrict__ W,
    const float* __restrict__ bias, float* __restrict__ out,
    int* __restrict__ cnt)
{
    int bx = blockIdx.x;
    if (bx < 512) {
        int tid = bx * TPB + threadIdx.x;   // 131072
        int c = tid & 63;
        int b = (tid >> 6) & 7;
        int n = tid >> 9;
        int j = n * 64 + c;
        float acc = bias[j];
        const float* lb = lat + b * 64;
#pragma unroll 16
        for (int l = 0; l < 64; ++l)
            acc = fmaf(lb[l], W[l * 16384 + j], acc);
        out[tid] = acc;
    } else {
        int tid = (bx - 512) * TPB + threadIdx.x;
        if (tid < 21504) cnt[tid] = 0;
    }
}

// Fused fold (layer 0 only): blocks [0,GF) write F=feat@W in MFMA B-frag
// order (bf16); blocks [GF,..) write UbW = Ub@W (row-major fp32).
template<int CI, int CO, int KF, int GF, int NBUB>
__global__ __launch_bounds__(TPB) void k_foldB(
    const float* __restrict__ X, const float* __restrict__ W,
    const float* __restrict__ Ub,
    ushort* __restrict__ Fq, float* __restrict__ UbW)
{
    int bx = blockIdx.x;
    if (bx < GF) {
        int tid = bx * TPB + threadIdx.x;
        int co = tid % CO;
        int nb = tid / CO;
        const float* x = X + (size_t)nb * CI;
        float acc = 0.f;
#pragma unroll
        for (int ci = 0; ci < CI; ++ci)
            acc = fmaf(x[ci], W[ci * CO + co], acc);
        int n = nb >> 3, bb = nb & 7;
        int col = bb * CO + co;
        int ks = n >> 5, r = n & 31, kq = r >> 3, j = r & 7;
        int ct = col >> 4, cl = col & 15;
        size_t idx = ((((size_t)ct * (KF / 32) + ks) * 4 + kq) * 16 + cl) * 8 + j;
        Fq[idx] = f2bf(acc);
    } else {
        int tid = (bx - GF) * TPB + threadIdx.x;
        if (tid >= NBUB * CO) return;
        int co = tid % CO;
        int row = tid / CO;
        const float* x = Ub + (size_t)row * CI;
        float acc = 0.f;
#pragma unroll
        for (int ci = 0; ci < CI; ++ci)
            acc = fmaf(x[ci], W[ci * CO + co], acc);
        UbW[tid] = acc;
    }
}

// ---------------- fused CSR-gather + relu/bias + fold-to-frags ----------------
// blocks [0,NR): one block per node r: feat[c] = relu(sum_e val*up[col_e][c] + bias[c%CI_IN]);
//   then frag(colp) = sum_ci feat[b*CI+ci]*W[ci*CO+co]  (colp=b*CO+co; pad cols -> 0)
// blocks [NR,..): UbW = Ub@W tail.
// CI_IN = channels of feat (== CI), BCIN = B*CI.
template<int BCIN, int CI, int CO, int COLS, int KF, int NR, int RBASE, int NBUB>
__global__ __launch_bounds__(TPB) void k_gf(
    const float* __restrict__ up, const int* __restrict__ offs,
    const int* __restrict__ ccol, const float* __restrict__ cval,
    const float* __restrict__ bias, const float* __restrict__ W,
    const float* __restrict__ Ub,
    ushort* __restrict__ Fq, float* __restrict__ UbW)
{
    int bx = blockIdx.x;
    if (bx < NR) {
        __shared__ float feat[BCIN];
        __shared__ float Wl[CI * CO];
        const int tid = threadIdx.x;
        const int r = bx;
#pragma unroll
        for (int i = tid; i < CI * CO; i += TPB) Wl[i] = W[i];
        int p0 = offs[RBASE + r], p1 = offs[RBASE + r + 1];
#pragma unroll
        for (int c = tid; c < BCIN; c += TPB) {
            float acc = 0.f;
            for (int p = p0; p < p1; ++p)
                acc = fmaf(cval[p], up[(size_t)ccol[p] * BCIN + c], acc);
            feat[c] = fmaxf(acc + bias[c % CI], 0.f);
        }
        __syncthreads();
        const int n = r;
        const int ks = n >> 5, rr = n & 31, kq = rr >> 3, j = rr & 7;
#pragma unroll
        for (int colp = tid; colp < COLS; colp += TPB) {
            float acc = 0.f;
            if (colp < 8 * CO) {
                int b = colp / CO, co = colp % CO;
                const float* fb = feat + b * CI;
#pragma unroll
                for (int ci = 0; ci < CI; ++ci)
                    acc = fmaf(fb[ci], Wl[ci * CO + co], acc);
            }
            int ct = colp >> 4, cl = colp & 15;
            size_t idx = ((((size_t)ct * (KF / 32) + ks) * 4 + kq) * 16 + cl) * 8 + j;
            Fq[idx] = f2bf(acc);
        }
    } else {
        int tid = (bx - NR) * TPB + threadIdx.x;
        if (tid >= NBUB * CO) return;
        int co = tid % CO;
        int row = tid / CO;
        const float* x = Ub + (size_t)row * CI;
        float acc = 0.f;
#pragma unroll
        for (int ci = 0; ci < CI; ++ci)
            acc = fmaf(x[ci], W[ci * CO + co], acc);
        UbW[tid] = acc;
    }
}

// ---------------- LDS-free MFMA GEMM, intra-block wave K-split ----------------
template<int K, int NTOT, int CO, int CF>
__global__ __launch_bounds__(TPB) void k_gemm_ws(
    const float* __restrict__ U, const ushort* __restrict__ Fq,
    const float* __restrict__ UbW, float* __restrict__ up)
{
    constexpr int KCH = K / 4;
    constexpr int KS = KCH / 32;
    constexpr int NC = CF * 16;
    static_assert(KS % 2 == 0, "even k-steps");

    __shared__ float red[4][NC * 16];

    const int tid = threadIdx.x;
    const int lane = tid & 63;
    const int w = tid >> 6;
    const int rowbase = blockIdx.x * 16;
    const int jt = blockIdx.y;
    const int kq = lane >> 4;
    const int m = lane & 15;

    const float* Ap = U + (size_t)(rowbase + m) * K + w * KCH + kq * 8;
    const ushort* Bp[CF];
#pragma unroll
    for (int cf = 0; cf < CF; ++cf)
        Bp[cf] = Fq + ((size_t)(jt * CF + cf) * (K / 32) + (size_t)w * KS) * 512
                 + lane * 8;

    f32x4 acc[CF];
#pragma unroll
    for (int cf = 0; cf < CF; ++cf)
        acc[cf] = (f32x4){0.f, 0.f, 0.f, 0.f};

    float4 a[2][2];
    uint4  b[2][CF];

#define LOAD_STEP(S, t)                                                     \
    if ((t) < KS) {                                                         \
        a[S][0] = *reinterpret_cast<const float4*>(Ap + (t) * 32);          \
        a[S][1] = *reinterpret_cast<const float4*>(Ap + (t) * 32 + 4);      \
        _Pragma("unroll")                                                   \
        for (int cf = 0; cf < CF; ++cf)                                     \
            b[S][cf] = *reinterpret_cast<const uint4*>(Bp[cf] + (t) * 512); \
    }

#define COMP_STEP(S)                                                        \
    {                                                                       \
        const float* fa = reinterpret_cast<const float*>(&a[S][0]);         \
        bf16x8 av;                                                          \
        _Pragma("unroll")                                                   \
        for (int j = 0; j < 8; ++j) av[j] = (__bf16)fa[j];                  \
        _Pragma("unroll")                                                   \
        for (int cf = 0; cf < CF; ++cf) {                                   \
            FragU bfr; bfr.q = b[S][cf];                                    \
            acc[cf] = __builtin_amdgcn_mfma_f32_16x16x32_bf16(              \
                av, bfr.v, acc[cf], 0, 0, 0);                               \
        }                                                                   \
    }

    LOAD_STEP(0, 0)
#pragma unroll
    for (int t = 0; t < KS; t += 2) {
        LOAD_STEP(1, t + 1)
        COMP_STEP(0)
        LOAD_STEP(0, t + 2)
        COMP_STEP(1)
    }
#undef LOAD_STEP
#undef COMP_STEP

#pragma unroll
    for (int cf = 0; cf < CF; ++cf)
#pragma unroll
        for (int r = 0; r < 4; ++r)
            red[w][(cf * 16 + m) * 16 + kq * 4 + r] = acc[cf][r];
    __syncthreads();

#pragma unroll
    for (int e = tid; e < NC * 16; e += TPB) {
        int col = e >> 4, row = e & 15;
        float v = red[0][e] + red[1][e] + red[2][e] + red[3][e];
        int gcol = jt * NC + col;
        int grow = rowbase + row;
        if (gcol < NTOT)
            up[(size_t)grow * NTOT + gcol] =
                v + UbW[(size_t)grow * CO + gcol % CO];
    }
}

// ---------------- CSR build ----------------
__global__ __launch_bounds__(TPB) void k_hist(
    const int* __restrict__ r0, const int* __restrict__ r1,
    const int* __restrict__ r2, int* __restrict__ cnt)
{
    int e = blockIdx.x * TPB + threadIdx.x;      // 344064
    if (e < 16384)        atomicAdd(&cnt[r0[e]], 1);
    else if (e < 81920)   atomicAdd(&cnt[1024 + r1[e - 16384]], 1);
    else if (e < 344064)  atomicAdd(&cnt[5120 + r2[e - 81920]], 1);
}

__global__ __launch_bounds__(1024) void k_scan(
    const int* __restrict__ cnt, int* __restrict__ offs, int* __restrict__ cur)
{
    constexpr int N = 21504, PER = 21;
    __shared__ int wsum[16];
    int tid = threadIdx.x;
    int base = tid * PER;
    int c[PER];
    int s = 0;
#pragma unroll
    for (int i = 0; i < PER; ++i) { c[i] = s; s += cnt[base + i]; }
    int lane = tid & 63, w = tid >> 6;
    int v = s;
#pragma unroll
    for (int d = 1; d < 64; d <<= 1) {
        int t = __shfl_up(v, d);
        if (lane >= d) v += t;
    }
    if (lane == 63) wsum[w] = v;
    __syncthreads();
    int woff = 0;
    for (int i = 0; i < w; ++i) woff += wsum[i];
    int excl = woff + v - s;
#pragma unroll
    for (int i = 0; i < PER; ++i) {
        int o = excl + c[i];
        offs[base + i] = o;
        cur[base + i] = o;
    }
    if (tid == 1023) offs[N] = excl + s;
}

__global__ __launch_bounds__(TPB) void k_fill(
    const int* __restrict__ r0, const int* __restrict__ c0, const float* __restrict__ v0,
    const int* __restrict__ r1, const int* __restrict__ c1, const float* __restrict__ v1,
    const int* __restrict__ r2, const int* __restrict__ c2, const float* __restrict__ v2,
    int* __restrict__ cur, int* __restrict__ ccol, float* __restrict__ cval)
{
    int e = blockIdx.x * TPB + threadIdx.x;
    int rbase, col; float val;
    if (e < 16384)       { rbase = 0;    col = c0[e];         val = v0[e];         rbase += r0[e]; }
    else if (e < 81920)  { int l = e - 16384; rbase = 1024;  col = c1[l]; val = v1[l]; rbase += r1[l]; }
    else if (e < 344064) { int l = e - 81920; rbase = 5120;  col = c2[l]; val = v2[l]; rbase += r2[l]; }
    else return;
    int pos = atomicAdd(&cur[rbase], 1);
    ccol[pos] = col;
    cval[pos] = val;
}

// ---------------- final CSR gather: relu+bias + output transpose ----------------
template<int BC, int CO, int NR, int RBASE>
__global__ __launch_bounds__(TPB) void k_gather_out(
    const float* __restrict__ up, const int* __restrict__ offs,
    const int* __restrict__ ccol, const float* __restrict__ cval,
    const float* __restrict__ bias, float* __restrict__ out)
{
    constexpr int JQ = BC / 4;
    int tid = blockIdx.x * TPB + threadIdx.x;
    if (tid >= NR * JQ) return;
    int jq = tid % JQ;
    int r = tid / JQ;
    int p0 = offs[RBASE + r], p1 = offs[RBASE + r + 1];
    float4 acc = make_float4(0.f, 0.f, 0.f, 0.f);
    for (int p = p0; p < p1; ++p) {
        float v = cval[p];
        int c = ccol[p];
        float4 u = *reinterpret_cast<const float4*>(&up[(size_t)c * BC + jq * 4]);
        acc.x = fmaf(v, u.x, acc.x);
        acc.y = fmaf(v, u.y, acc.y);
        acc.z = fmaf(v, u.z, acc.z);
        acc.w = fmaf(v, u.w, acc.w);
    }
    int col0 = jq * 4;
    float a[4] = {acc.x, acc.y, acc.z, acc.w};
#pragma unroll
    for (int e = 0; e < 4; ++e) {
        int col = col0 + e;
        int b = col / 3, j = col - b * 3;
        out[(size_t)b * 49152 + (size_t)r * 3 + j] = fmaxf(a[e] + bias[j], 0.f);
    }
}

extern "C" void kernel_launch(void* const* d_in, const int* in_sizes, int n_in,
                              void* d_out, int out_size, void* d_ws, size_t ws_size,
                              hipStream_t stream)
{
    const float* lat   = (const float*)d_in[0];
    const float* fcW   = (const float*)d_in[1];
    const float* fcb   = (const float*)d_in[2];
    const float* U0    = (const float*)d_in[3];
    const float* Ub0   = (const float*)d_in[4];
    const float* W0    = (const float*)d_in[5];
    const float* b0    = (const float*)d_in[6];
    const float* vals0 = (const float*)d_in[7];
    const int*   rows0 = (const int*)d_in[8];
    const int*   cols0 = (const int*)d_in[9];
    const float* U1    = (const float*)d_in[10];
    const float* Ub1   = (const float*)d_in[11];
    const float* W1    = (const float*)d_in[12];
    const float* b1    = (const float*)d_in[13];
    const float* vals1 = (const float*)d_in[14];
    const int*   rows1 = (const int*)d_in[15];
    const int*   cols1 = (const int*)d_in[16];
    const float* U2    = (const float*)d_in[17];
    const float* Ub2   = (const float*)d_in[18];
    const float* W2    = (const float*)d_in[19];
    const float* b2    = (const float*)d_in[20];
    const float* vals2 = (const float*)d_in[21];
    const int*   rows2 = (const int*)d_in[22];
    const int*   cols2 = (const int*)d_in[23];

    float* ws = (float*)d_ws;
    float* fbuf0 = ws;                     // 131072 (fc output)
    float* fWq   = fbuf0 + 131072;         // 262144 (frag buffer storage)
    float* UbW   = fWq   + 262144;         // 131072
    float* up    = UbW   + 131072;         // 1048576
    int*   offs  = (int*)(up + 1048576);   // 21760
    int*   cur   = offs + 21760;           // 21760
    int*   cnt   = cur + 21760;            // 21760
    int*   ccol  = cnt + 21760;            // 344064
    float* cval  = (float*)(ccol + 344064);// 344064

    ushort* Fq16 = (ushort*)fWq;
    float* out = (float*)d_out;

    // fc + cnt-zero
    hipLaunchKernelGGL(k_prep, dim3(596), dim3(TPB), 0, stream, lat, fcW, fcb, fbuf0, cnt);
    // CSR build
    hipLaunchKernelGGL(k_hist, dim3(1344), dim3(TPB), 0, stream, rows0, rows1, rows2, cnt);
    hipLaunchKernelGGL(k_scan, dim3(1), dim3(1024), 0, stream, cnt, offs, cur);
    hipLaunchKernelGGL(k_fill, dim3(1344), dim3(TPB), 0, stream,
                       rows0, cols0, vals0, rows1, cols1, vals1, rows2, cols2, vals2,
                       cur, ccol, cval);

    // ---- layer 0: fold0 (F0 frags + UbW0), GEMM ----
    hipLaunchKernelGGL((k_foldB<64, 64, 256, 512, 1024>), dim3(768), dim3(TPB), 0, stream,
                       fbuf0, W0, Ub0, Fq16, UbW);
    hipLaunchKernelGGL((k_gemm_ws<256, 512, 64, 8>), dim3(64, 4), dim3(TPB), 0, stream,
                       U0, Fq16, UbW, up);

    // ---- fused gather0 + fold1: feat1 -> F1 frags + UbW1 ----
    hipLaunchKernelGGL((k_gf<512, 64, 32, 256, 1024, 1024, 0, 4096>), dim3(1536), dim3(TPB), 0, stream,
                       up, offs, ccol, cval, b0, W1, Ub1, Fq16, UbW);
    hipLaunchKernelGGL((k_gemm_ws<1024, 256, 32, 8>), dim3(256, 2), dim3(TPB), 0, stream,
                       U1, Fq16, UbW, up);

    // ---- fused gather1 + fold2: feat2 -> F2 frags (32-col padded) + UbW2 ----
    hipLaunchKernelGGL((k_gf<256, 32, 3, 32, 4096, 4096, 1024, 16384>), dim3(4288), dim3(TPB), 0, stream,
                       up, offs, ccol, cval, b1, W2, Ub2, Fq16, UbW);
    hipLaunchKernelGGL((k_gemm_ws<4096, 24, 3, 2>), dim3(1024, 1), dim3(TPB), 0, stream,
                       U2, Fq16, UbW, up);

    // ---- final gather + relu + bias + transpose to [B][N][3] ----
    hipLaunchKernelGGL((k_gather_out<24, 3, 16384, 5120>), dim3(384), dim3(TPB), 0, stream,
                       up, offs, ccol, cval, b2, out);
}

// Round 9
// 165.343 us; speedup vs baseline: 1.3241x; 1.1640x over previous
//
#include <hip/hip_runtime.h>
#include <cstdint>
#include <cstddef>

#define TPB 256
#define CAP 128   // bucket capacity per node (mean degree 16)

typedef __bf16 bf16x8 __attribute__((ext_vector_type(8)));
typedef float f32x4 __attribute__((ext_vector_type(4)));

union FragU { ushort u[8]; uint4 q; bf16x8 v; };

__device__ __forceinline__ ushort f2bf(float f)
{
    union { float f; uint32_t u; } v; v.f = f;
    uint32_t r = v.u + 0x7FFFu + ((v.u >> 16) & 1u);   // RNE
    return (ushort)(r >> 16);
}

// prep: fc (blocks 0..511) + zero cnt (blocks 512..595)
__global__ __launch_bounds__(TPB) void k_prep(
    const float* __restrict__ lat, const float* __restrict__ W,
    const float* __restrict__ bias, float* __restrict__ out,
    int* __restrict__ cnt)
{
    int bx = blockIdx.x;
    if (bx < 512) {
        int tid = bx * TPB + threadIdx.x;   // 131072
        int c = tid & 63;
        int b = (tid >> 6) & 7;
        int n = tid >> 9;
        int j = n * 64 + c;
        float acc = bias[j];
        const float* lb = lat + b * 64;
#pragma unroll 16
        for (int l = 0; l < 64; ++l)
            acc = fmaf(lb[l], W[l * 16384 + j], acc);
        out[tid] = acc;
    } else {
        int tid = (bx - 512) * TPB + threadIdx.x;
        if (tid < 21504) cnt[tid] = 0;
    }
}

// build: blocks [0,1344) bucket-fill all 3 edge lists;
//        blocks [1344,1856) fold0 F-frags; [1856,2112) UbW0 tail.
__global__ __launch_bounds__(TPB) void k_build(
    const int* __restrict__ r0, const int* __restrict__ c0, const float* __restrict__ v0,
    const int* __restrict__ r1, const int* __restrict__ c1, const float* __restrict__ v1,
    const int* __restrict__ r2, const int* __restrict__ c2, const float* __restrict__ v2,
    int* __restrict__ cnt, int* __restrict__ ccol, float* __restrict__ cval,
    const float* __restrict__ X, const float* __restrict__ W0,
    const float* __restrict__ Ub0,
    ushort* __restrict__ Fq, float* __restrict__ UbW)
{
    int bx = blockIdx.x;
    if (bx < 1344) {
        int e = bx * TPB + threadIdx.x;
        int node, col; float val;
        if (e < 16384)       { node = r0[e];                col = c0[e];  val = v0[e]; }
        else if (e < 81920)  { int l = e - 16384; node = 1024 + r1[l]; col = c1[l]; val = v1[l]; }
        else                 { int l = e - 81920; node = 5120 + r2[l]; col = c2[l]; val = v2[l]; }
        int pos = atomicAdd(&cnt[node], 1);
        ccol[(size_t)node * CAP + pos] = col;
        cval[(size_t)node * CAP + pos] = val;
    } else if (bx < 1856) {
        // fold0: F = feat0@W0 in MFMA B-frag order, CI=64 CO=64 KF=256
        int tid = (bx - 1344) * TPB + threadIdx.x;
        int co = tid % 64;
        int nb = tid / 64;
        const float* x = X + (size_t)nb * 64;
        float acc = 0.f;
#pragma unroll
        for (int ci = 0; ci < 64; ++ci)
            acc = fmaf(x[ci], W0[ci * 64 + co], acc);
        int n = nb >> 3, bb = nb & 7;
        int col = bb * 64 + co;
        int ks = n >> 5, r = n & 31, kq = r >> 3, j = r & 7;
        int ct = col >> 4, cl = col & 15;
        size_t idx = ((((size_t)ct * (256 / 32) + ks) * 4 + kq) * 16 + cl) * 8 + j;
        Fq[idx] = f2bf(acc);
    } else {
        int tid = (bx - 1856) * TPB + threadIdx.x;
        if (tid >= 65536) return;
        int co = tid % 64;
        int row = tid / 64;
        const float* x = Ub0 + (size_t)row * 64;
        float acc = 0.f;
#pragma unroll
        for (int ci = 0; ci < 64; ++ci)
            acc = fmaf(x[ci], W0[ci * 64 + co], acc);
        UbW[tid] = acc;
    }
}

// ---------------- fused CSR-gather + relu/bias + fold-to-frags ----------------
template<int BCIN, int CI, int CO, int COLS, int KF, int NR, int RBASE, int NBUB>
__global__ __launch_bounds__(TPB) void k_gf(
    const float* __restrict__ up, const int* __restrict__ cnt,
    const int* __restrict__ ccol, const float* __restrict__ cval,
    const float* __restrict__ bias, const float* __restrict__ W,
    const float* __restrict__ Ub,
    ushort* __restrict__ Fq, float* __restrict__ UbW)
{
    int bx = blockIdx.x;
    if (bx < NR) {
        __shared__ float feat[BCIN];
        __shared__ float Wl[CI * CO];
        const int tid = threadIdx.x;
        const int r = bx;
#pragma unroll
        for (int i = tid; i < CI * CO; i += TPB) Wl[i] = W[i];
        size_t p0 = (size_t)(RBASE + r) * CAP;
        size_t p1 = p0 + cnt[RBASE + r];
#pragma unroll
        for (int c = tid; c < BCIN; c += TPB) {
            float acc = 0.f;
            for (size_t p = p0; p < p1; ++p)
                acc = fmaf(cval[p], up[(size_t)ccol[p] * BCIN + c], acc);
            feat[c] = fmaxf(acc + bias[c % CI], 0.f);
        }
        __syncthreads();
        const int n = r;
        const int ks = n >> 5, rr = n & 31, kq = rr >> 3, j = rr & 7;
#pragma unroll
        for (int colp = tid; colp < COLS; colp += TPB) {
            float acc = 0.f;
            if (colp < 8 * CO) {
                int b = colp / CO, co = colp % CO;
                const float* fb = feat + b * CI;
#pragma unroll
                for (int ci = 0; ci < CI; ++ci)
                    acc = fmaf(fb[ci], Wl[ci * CO + co], acc);
            }
            int ct = colp >> 4, cl = colp & 15;
            size_t idx = ((((size_t)ct * (KF / 32) + ks) * 4 + kq) * 16 + cl) * 8 + j;
            Fq[idx] = f2bf(acc);
        }
    } else {
        int tid = (bx - NR) * TPB + threadIdx.x;
        if (tid >= NBUB * CO) return;
        int co = tid % CO;
        int row = tid / CO;
        const float* x = Ub + (size_t)row * CI;
        float acc = 0.f;
#pragma unroll
        for (int ci = 0; ci < CI; ++ci)
            acc = fmaf(x[ci], W[ci * CO + co], acc);
        UbW[tid] = acc;
    }
}

// ---------------- LDS-free MFMA GEMM, intra-block wave K-split ----------------
// Block = 4 waves over the same RF*16 rows x NC cols; wave w handles K/4.
template<int K, int NTOT, int CO, int CF, int RF>
__global__ __launch_bounds__(TPB) void k_gemm_ws(
    const float* __restrict__ U, const ushort* __restrict__ Fq,
    const float* __restrict__ UbW, float* __restrict__ up)
{
    constexpr int KCH = K / 4;
    constexpr int KS = KCH / 32;
    constexpr int NC = CF * 16;
    constexpr int RED = RF * NC * 16;
    static_assert(KS % 2 == 0, "even k-steps");

    __shared__ float red[4][RED];

    const int tid = threadIdx.x;
    const int lane = tid & 63;
    const int w = tid >> 6;
    const int rowbase = blockIdx.x * (RF * 16);
    const int jt = blockIdx.y;
    const int kq = lane >> 4;
    const int m = lane & 15;

    const float* Ap[RF];
#pragma unroll
    for (int rf = 0; rf < RF; ++rf)
        Ap[rf] = U + (size_t)(rowbase + rf * 16 + m) * K + w * KCH + kq * 8;

    const ushort* Bp[CF];
#pragma unroll
    for (int cf = 0; cf < CF; ++cf)
        Bp[cf] = Fq + ((size_t)(jt * CF + cf) * (K / 32) + (size_t)w * KS) * 512
                 + lane * 8;

    f32x4 acc[RF][CF];
#pragma unroll
    for (int rf = 0; rf < RF; ++rf)
#pragma unroll
        for (int cf = 0; cf < CF; ++cf)
            acc[rf][cf] = (f32x4){0.f, 0.f, 0.f, 0.f};

    float4 a[2][RF][2];
    uint4  b[2][CF];

#define LOAD_STEP(S, t)                                                     \
    if ((t) < KS) {                                                         \
        _Pragma("unroll")                                                   \
        for (int rf = 0; rf < RF; ++rf) {                                   \
            a[S][rf][0] = *reinterpret_cast<const float4*>(Ap[rf] + (t) * 32);     \
            a[S][rf][1] = *reinterpret_cast<const float4*>(Ap[rf] + (t) * 32 + 4); \
        }                                                                   \
        _Pragma("unroll")                                                   \
        for (int cf = 0; cf < CF; ++cf)                                     \
            b[S][cf] = *reinterpret_cast<const uint4*>(Bp[cf] + (t) * 512); \
    }

#define COMP_STEP(S)                                                        \
    {                                                                       \
        _Pragma("unroll")                                                   \
        for (int rf = 0; rf < RF; ++rf) {                                   \
            const float* fa = reinterpret_cast<const float*>(&a[S][rf][0]); \
            bf16x8 av;                                                      \
            _Pragma("unroll")                                               \
            for (int j = 0; j < 8; ++j) av[j] = (__bf16)fa[j];              \
            _Pragma("unroll")                                               \
            for (int cf = 0; cf < CF; ++cf) {                               \
                FragU bfr; bfr.q = b[S][cf];                                \
                acc[rf][cf] = __builtin_amdgcn_mfma_f32_16x16x32_bf16(      \
                    av, bfr.v, acc[rf][cf], 0, 0, 0);                       \
            }                                                               \
        }                                                                   \
    }

    LOAD_STEP(0, 0)
#pragma unroll
    for (int t = 0; t < KS; t += 2) {
        LOAD_STEP(1, t + 1)
        COMP_STEP(0)
        LOAD_STEP(0, t + 2)
        COMP_STEP(1)
    }
#undef LOAD_STEP
#undef COMP_STEP

#pragma unroll
    for (int rf = 0; rf < RF; ++rf)
#pragma unroll
        for (int cf = 0; cf < CF; ++cf)
#pragma unroll
            for (int r = 0; r < 4; ++r)
                red[w][(rf * NC + cf * 16 + m) * 16 + kq * 4 + r] = acc[rf][cf][r];
    __syncthreads();

#pragma unroll
    for (int e = tid; e < RED; e += TPB) {
        int rf = e / (NC * 16);
        int rem = e - rf * (NC * 16);
        int col = rem >> 4, row = rem & 15;
        float v = red[0][e] + red[1][e] + red[2][e] + red[3][e];
        int gcol = jt * NC + col;
        int grow = rowbase + rf * 16 + row;
        if (gcol < NTOT)
            up[(size_t)grow * NTOT + gcol] =
                v + UbW[(size_t)grow * CO + gcol % CO];
    }
}

// ---------------- final gather: relu+bias + output transpose ----------------
template<int BC, int CO, int NR, int RBASE>
__global__ __launch_bounds__(TPB) void k_gather_out(
    const float* __restrict__ up, const int* __restrict__ cnt,
    const int* __restrict__ ccol, const float* __restrict__ cval,
    const float* __restrict__ bias, float* __restrict__ out)
{
    constexpr int JQ = BC / 4;
    int tid = blockIdx.x * TPB + threadIdx.x;
    if (tid >= NR * JQ) return;
    int jq = tid % JQ;
    int r = tid / JQ;
    size_t p0 = (size_t)(RBASE + r) * CAP;
    size_t p1 = p0 + cnt[RBASE + r];
    float4 acc = make_float4(0.f, 0.f, 0.f, 0.f);
    for (size_t p = p0; p < p1; ++p) {
        float v = cval[p];
        int c = ccol[p];
        float4 u = *reinterpret_cast<const float4*>(&up[(size_t)c * BC + jq * 4]);
        acc.x = fmaf(v, u.x, acc.x);
        acc.y = fmaf(v, u.y, acc.y);
        acc.z = fmaf(v, u.z, acc.z);
        acc.w = fmaf(v, u.w, acc.w);
    }
    int col0 = jq * 4;
    float a[4] = {acc.x, acc.y, acc.z, acc.w};
#pragma unroll
    for (int e = 0; e < 4; ++e) {
        int col = col0 + e;
        int b = col / 3, j = col - b * 3;
        out[(size_t)b * 49152 + (size_t)r * 3 + j] = fmaxf(a[e] + bias[j], 0.f);
    }
}

extern "C" void kernel_launch(void* const* d_in, const int* in_sizes, int n_in,
                              void* d_out, int out_size, void* d_ws, size_t ws_size,
                              hipStream_t stream)
{
    const float* lat   = (const float*)d_in[0];
    const float* fcW   = (const float*)d_in[1];
    const float* fcb   = (const float*)d_in[2];
    const float* U0    = (const float*)d_in[3];
    const float* Ub0   = (const float*)d_in[4];
    const float* W0    = (const float*)d_in[5];
    const float* b0    = (const float*)d_in[6];
    const float* vals0 = (const float*)d_in[7];
    const int*   rows0 = (const int*)d_in[8];
    const int*   cols0 = (const int*)d_in[9];
    const float* U1    = (const float*)d_in[10];
    const float* Ub1   = (const float*)d_in[11];
    const float* W1    = (const float*)d_in[12];
    const float* b1    = (const float*)d_in[13];
    const float* vals1 = (const float*)d_in[14];
    const int*   rows1 = (const int*)d_in[15];
    const int*   cols1 = (const int*)d_in[16];
    const float* U2    = (const float*)d_in[17];
    const float* Ub2   = (const float*)d_in[18];
    const float* W2    = (const float*)d_in[19];
    const float* b2    = (const float*)d_in[20];
    const float* vals2 = (const float*)d_in[21];
    const int*   rows2 = (const int*)d_in[22];
    const int*   cols2 = (const int*)d_in[23];

    float* ws = (float*)d_ws;
    float* fbuf0 = ws;                      // 131072 (fc output)
    float* fWq   = fbuf0 + 131072;          // 262144 (frag buffer storage)
    float* UbW   = fWq   + 262144;          // 131072
    float* up    = UbW   + 131072;          // 1048576
    int*   cnt   = (int*)(up + 1048576);    // 21760
    int*   ccol  = cnt + 21760;             // 21504*128 = 2752512
    float* cval  = (float*)(ccol + 2752512);// 2752512

    ushort* Fq16 = (ushort*)fWq;
    float* out = (float*)d_out;

    // 1: fc + cnt-zero
    hipLaunchKernelGGL(k_prep, dim3(596), dim3(TPB), 0, stream, lat, fcW, fcb, fbuf0, cnt);
    // 2: bucket CSR build + fold0 (F0 frags + UbW0)
    hipLaunchKernelGGL(k_build, dim3(2112), dim3(TPB), 0, stream,
                       rows0, cols0, vals0, rows1, cols1, vals1, rows2, cols2, vals2,
                       cnt, ccol, cval, fbuf0, W0, Ub0, Fq16, UbW);
    // 3: layer-0 GEMM: M=1024 K=256 NTOT=512, CF=8 RF=1 -> grid (64,4)
    hipLaunchKernelGGL((k_gemm_ws<256, 512, 64, 8, 1>), dim3(64, 4), dim3(TPB), 0, stream,
                       U0, Fq16, UbW, up);
    // 4: fused gather0 + fold1
    hipLaunchKernelGGL((k_gf<512, 64, 32, 256, 1024, 1024, 0, 4096>), dim3(1536), dim3(TPB), 0, stream,
                       up, cnt, ccol, cval, b0, W1, Ub1, Fq16, UbW);
    // 5: layer-1 GEMM: M=4096 K=1024 NTOT=256, CF=8 RF=1 -> grid (256,2)
    hipLaunchKernelGGL((k_gemm_ws<1024, 256, 32, 8, 1>), dim3(256, 2), dim3(TPB), 0, stream,
                       U1, Fq16, UbW, up);
    // 6: fused gather1 + fold2
    hipLaunchKernelGGL((k_gf<256, 32, 3, 32, 4096, 4096, 1024, 16384>), dim3(4288), dim3(TPB), 0, stream,
                       up, cnt, ccol, cval, b1, W2, Ub2, Fq16, UbW);
    // 7: layer-2 GEMM: M=16384 K=4096 NTOT=24(pad32), CF=2 RF=2 -> grid (512,1)
    hipLaunchKernelGGL((k_gemm_ws<4096, 24, 3, 2, 2>), dim3(512, 1), dim3(TPB), 0, stream,
                       U2, Fq16, UbW, up);
    // 8: final gather + relu + bias + transpose
    hipLaunchKernelGGL((k_gather_out<24, 3, 16384, 5120>), dim3(384), dim3(TPB), 0, stream,
                       up, cnt, ccol, cval, b2, out);
}

// Round 10
// 152.559 us; speedup vs baseline: 1.4351x; 1.0838x over previous
//
#include <hip/hip_runtime.h>
#include <cstdint>
#include <cstddef>

#define TPB 256
#define CAP 128   // bucket capacity per node (mean degree 16)

typedef __bf16 bf16x8 __attribute__((ext_vector_type(8)));
typedef float f32x4 __attribute__((ext_vector_type(4)));

union FragU { ushort u[8]; uint4 q; bf16x8 v; };

__device__ __forceinline__ ushort f2bf(float f)
{
    union { float f; uint32_t u; } v; v.f = f;
    uint32_t r = v.u + 0x7FFFu + ((v.u >> 16) & 1u);   // RNE
    return (ushort)(r >> 16);
}

// prep: fc (blocks 0..511) + zero cnt (blocks 512..595)
__global__ __launch_bounds__(TPB) void k_prep(
    const float* __restrict__ lat, const float* __restrict__ W,
    const float* __restrict__ bias, float* __restrict__ out,
    int* __restrict__ cnt)
{
    int bx = blockIdx.x;
    if (bx < 512) {
        int tid = bx * TPB + threadIdx.x;   // 131072
        int c = tid & 63;
        int b = (tid >> 6) & 7;
        int n = tid >> 9;
        int j = n * 64 + c;
        float acc = bias[j];
        const float* lb = lat + b * 64;
#pragma unroll 16
        for (int l = 0; l < 64; ++l)
            acc = fmaf(lb[l], W[l * 16384 + j], acc);
        out[tid] = acc;
    } else {
        int tid = (bx - 512) * TPB + threadIdx.x;
        if (tid < 21504) cnt[tid] = 0;
    }
}

// build: blocks [0,1344) bucket-fill all 3 edge lists (packed int2);
//        blocks [1344,1856) fold0 F-frags; [1856,2112) UbW0 tail.
__global__ __launch_bounds__(TPB) void k_build(
    const int* __restrict__ r0, const int* __restrict__ c0, const float* __restrict__ v0,
    const int* __restrict__ r1, const int* __restrict__ c1, const float* __restrict__ v1,
    const int* __restrict__ r2, const int* __restrict__ c2, const float* __restrict__ v2,
    int* __restrict__ cnt, int2* __restrict__ ecv,
    const float* __restrict__ X, const float* __restrict__ W0,
    const float* __restrict__ Ub0,
    ushort* __restrict__ Fq, float* __restrict__ UbW)
{
    int bx = blockIdx.x;
    if (bx < 1344) {
        int e = bx * TPB + threadIdx.x;
        int node, col; float val;
        if (e < 16384)       { node = r0[e];                col = c0[e];  val = v0[e]; }
        else if (e < 81920)  { int l = e - 16384; node = 1024 + r1[l]; col = c1[l]; val = v1[l]; }
        else                 { int l = e - 81920; node = 5120 + r2[l]; col = c2[l]; val = v2[l]; }
        int pos = atomicAdd(&cnt[node], 1);
        ecv[(size_t)node * CAP + pos] = make_int2(col, __float_as_int(val));
    } else if (bx < 1856) {
        // fold0: F = feat0@W0 in MFMA B-frag order, CI=64 CO=64 KF=256
        int tid = (bx - 1344) * TPB + threadIdx.x;
        int co = tid % 64;
        int nb = tid / 64;
        const float* x = X + (size_t)nb * 64;
        float acc = 0.f;
#pragma unroll
        for (int ci = 0; ci < 64; ++ci)
            acc = fmaf(x[ci], W0[ci * 64 + co], acc);
        int n = nb >> 3, bb = nb & 7;
        int col = bb * 64 + co;
        int ks = n >> 5, r = n & 31, kq = r >> 3, j = r & 7;
        int ct = col >> 4, cl = col & 15;
        size_t idx = ((((size_t)ct * (256 / 32) + ks) * 4 + kq) * 16 + cl) * 8 + j;
        Fq[idx] = f2bf(acc);
    } else {
        int tid = (bx - 1856) * TPB + threadIdx.x;
        if (tid >= 65536) return;
        int co = tid % 64;
        int row = tid / 64;
        const float* x = Ub0 + (size_t)row * 64;
        float acc = 0.f;
#pragma unroll
        for (int ci = 0; ci < 64; ++ci)
            acc = fmaf(x[ci], W0[ci * 64 + co], acc);
        UbW[tid] = acc;
    }
}

// ---------------- fused gather + relu/bias + fold-to-frags ----------------
// NPB nodes per block; TPN=TPB/NPB threads per node; CPT=BCIN/TPN ch/thread.
// Gather: edge loop OUTER, unrolled channel FMA inner (CPT-wide ILP).
// Fold: NPB*COLS outputs, all lanes active.
template<int NPB, int BCIN, int CI, int CO, int COLS, int KF,
         int NNODE, int RBASE, int NBUB>
__global__ __launch_bounds__(TPB) void k_gf(
    const float* __restrict__ up, const int* __restrict__ cnt,
    const int2* __restrict__ ecv,
    const float* __restrict__ bias, const float* __restrict__ W,
    const float* __restrict__ Ub,
    ushort* __restrict__ Fq, float* __restrict__ UbW)
{
    constexpr int TPN = TPB / NPB;
    constexpr int CPT = BCIN / TPN;
    int bx = blockIdx.x;
    if (bx < NNODE / NPB) {
        __shared__ float feat[NPB * BCIN];
        __shared__ float Wl[CI * CO];
        const int tid = threadIdx.x;
#pragma unroll
        for (int i = tid; i < CI * CO; i += TPB) Wl[i] = W[i];

        const int ni = tid / TPN;
        const int li = tid % TPN;
        const int node = bx * NPB + ni;
        const int deg = cnt[RBASE + node];
        const int2* ep = ecv + (size_t)(RBASE + node) * CAP;

        float acc[CPT];
#pragma unroll
        for (int k = 0; k < CPT; ++k) acc[k] = 0.f;
        for (int p = 0; p < deg; ++p) {
            int2 cv = ep[p];                       // broadcast within TPN group
            float v = __int_as_float(cv.y);
            const float* ur = up + (size_t)cv.x * BCIN + li;
#pragma unroll
            for (int k = 0; k < CPT; ++k)
                acc[k] = fmaf(v, ur[k * TPN], acc[k]);
        }
#pragma unroll
        for (int k = 0; k < CPT; ++k) {
            int c = li + k * TPN;
            feat[ni * BCIN + c] = fmaxf(acc[k] + bias[c % CI], 0.f);
        }
        __syncthreads();

#pragma unroll
        for (int e = tid; e < NPB * COLS; e += TPB) {
            int fni = e / COLS;
            int colp = e % COLS;
            int n = bx * NPB + fni;
            float a = 0.f;
            if (colp < 8 * CO) {
                int b = colp / CO, co = colp % CO;
                const float* fb = feat + fni * BCIN + b * CI;
#pragma unroll
                for (int ci = 0; ci < CI; ++ci)
                    a = fmaf(fb[ci], Wl[ci * CO + co], a);
            }
            int ks = n >> 5, rr = n & 31, kq = rr >> 3, j = rr & 7;
            int ct = colp >> 4, cl = colp & 15;
            size_t idx = ((((size_t)ct * (KF / 32) + ks) * 4 + kq) * 16 + cl) * 8 + j;
            Fq[idx] = f2bf(a);
        }
    } else {
        int tid = (bx - NNODE / NPB) * TPB + threadIdx.x;
        if (tid >= NBUB * CO) return;
        int co = tid % CO;
        int row = tid / CO;
        const float* x = Ub + (size_t)row * CI;
        float acc = 0.f;
#pragma unroll
        for (int ci = 0; ci < CI; ++ci)
            acc = fmaf(x[ci], W[ci * CO + co], acc);
        UbW[tid] = acc;
    }
}

// ---------------- LDS-free MFMA GEMM, intra-block wave K-split ----------------
template<int K, int NTOT, int CO, int CF, int RF>
__global__ __launch_bounds__(TPB) void k_gemm_ws(
    const float* __restrict__ U, const ushort* __restrict__ Fq,
    const float* __restrict__ UbW, float* __restrict__ up)
{
    constexpr int KCH = K / 4;
    constexpr int KS = KCH / 32;
    constexpr int NC = CF * 16;
    constexpr int RED = RF * NC * 16;
    static_assert(KS % 2 == 0, "even k-steps");

    __shared__ float red[4][RED];

    const int tid = threadIdx.x;
    const int lane = tid & 63;
    const int w = tid >> 6;
    const int rowbase = blockIdx.x * (RF * 16);
    const int jt = blockIdx.y;
    const int kq = lane >> 4;
    const int m = lane & 15;

    const float* Ap[RF];
#pragma unroll
    for (int rf = 0; rf < RF; ++rf)
        Ap[rf] = U + (size_t)(rowbase + rf * 16 + m) * K + w * KCH + kq * 8;

    const ushort* Bp[CF];
#pragma unroll
    for (int cf = 0; cf < CF; ++cf)
        Bp[cf] = Fq + ((size_t)(jt * CF + cf) * (K / 32) + (size_t)w * KS) * 512
                 + lane * 8;

    f32x4 acc[RF][CF];
#pragma unroll
    for (int rf = 0; rf < RF; ++rf)
#pragma unroll
        for (int cf = 0; cf < CF; ++cf)
            acc[rf][cf] = (f32x4){0.f, 0.f, 0.f, 0.f};

    float4 a[2][RF][2];
    uint4  b[2][CF];

#define LOAD_STEP(S, t)                                                     \
    if ((t) < KS) {                                                         \
        _Pragma("unroll")                                                   \
        for (int rf = 0; rf < RF; ++rf) {                                   \
            a[S][rf][0] = *reinterpret_cast<const float4*>(Ap[rf] + (t) * 32);     \
            a[S][rf][1] = *reinterpret_cast<const float4*>(Ap[rf] + (t) * 32 + 4); \
        }                                                                   \
        _Pragma("unroll")                                                   \
        for (int cf = 0; cf < CF; ++cf)                                     \
            b[S][cf] = *reinterpret_cast<const uint4*>(Bp[cf] + (t) * 512); \
    }

#define COMP_STEP(S)                                                        \
    {                                                                       \
        _Pragma("unroll")                                                   \
        for (int rf = 0; rf < RF; ++rf) {                                   \
            const float* fa = reinterpret_cast<const float*>(&a[S][rf][0]); \
            bf16x8 av;                                                      \
            _Pragma("unroll")                                               \
            for (int j = 0; j < 8; ++j) av[j] = (__bf16)fa[j];              \
            _Pragma("unroll")                                               \
            for (int cf = 0; cf < CF; ++cf) {                               \
                FragU bfr; bfr.q = b[S][cf];                                \
                acc[rf][cf] = __builtin_amdgcn_mfma_f32_16x16x32_bf16(      \
                    av, bfr.v, acc[rf][cf], 0, 0, 0);                       \
            }                                                               \
        }                                                                   \
    }

    LOAD_STEP(0, 0)
#pragma unroll
    for (int t = 0; t < KS; t += 2) {
        LOAD_STEP(1, t + 1)
        COMP_STEP(0)
        LOAD_STEP(0, t + 2)
        COMP_STEP(1)
    }
#undef LOAD_STEP
#undef COMP_STEP

#pragma unroll
    for (int rf = 0; rf < RF; ++rf)
#pragma unroll
        for (int cf = 0; cf < CF; ++cf)
#pragma unroll
            for (int r = 0; r < 4; ++r)
                red[w][(rf * NC + cf * 16 + m) * 16 + kq * 4 + r] = acc[rf][cf][r];
    __syncthreads();

#pragma unroll
    for (int e = tid; e < RED; e += TPB) {
        int rf = e / (NC * 16);
        int rem = e - rf * (NC * 16);
        int col = rem >> 4, row = rem & 15;
        float v = red[0][e] + red[1][e] + red[2][e] + red[3][e];
        int gcol = jt * NC + col;
        int grow = rowbase + rf * 16 + row;
        if (gcol < NTOT)
            up[(size_t)grow * NTOT + gcol] =
                v + UbW[(size_t)grow * CO + gcol % CO];
    }
}

// ---------------- final gather: relu+bias + output transpose ----------------
template<int BC, int CO, int NR, int RBASE>
__global__ __launch_bounds__(TPB) void k_gather_out(
    const float* __restrict__ up, const int* __restrict__ cnt,
    const int2* __restrict__ ecv,
    const float* __restrict__ bias, float* __restrict__ out)
{
    constexpr int JQ = BC / 4;
    int tid = blockIdx.x * TPB + threadIdx.x;
    if (tid >= NR * JQ) return;
    int jq = tid % JQ;
    int r = tid / JQ;
    int deg = cnt[RBASE + r];
    const int2* ep = ecv + (size_t)(RBASE + r) * CAP;
    float4 acc = make_float4(0.f, 0.f, 0.f, 0.f);
    for (int p = 0; p < deg; ++p) {
        int2 cv = ep[p];
        float v = __int_as_float(cv.y);
        float4 u = *reinterpret_cast<const float4*>(&up[(size_t)cv.x * BC + jq * 4]);
        acc.x = fmaf(v, u.x, acc.x);
        acc.y = fmaf(v, u.y, acc.y);
        acc.z = fmaf(v, u.z, acc.z);
        acc.w = fmaf(v, u.w, acc.w);
    }
    int col0 = jq * 4;
    float a[4] = {acc.x, acc.y, acc.z, acc.w};
#pragma unroll
    for (int e = 0; e < 4; ++e) {
        int col = col0 + e;
        int b = col / 3, j = col - b * 3;
        out[(size_t)b * 49152 + (size_t)r * 3 + j] = fmaxf(a[e] + bias[j], 0.f);
    }
}

extern "C" void kernel_launch(void* const* d_in, const int* in_sizes, int n_in,
                              void* d_out, int out_size, void* d_ws, size_t ws_size,
                              hipStream_t stream)
{
    const float* lat   = (const float*)d_in[0];
    const float* fcW   = (const float*)d_in[1];
    const float* fcb   = (const float*)d_in[2];
    const float* U0    = (const float*)d_in[3];
    const float* Ub0   = (const float*)d_in[4];
    const float* W0    = (const float*)d_in[5];
    const float* b0    = (const float*)d_in[6];
    const float* vals0 = (const float*)d_in[7];
    const int*   rows0 = (const int*)d_in[8];
    const int*   cols0 = (const int*)d_in[9];
    const float* U1    = (const float*)d_in[10];
    const float* Ub1   = (const float*)d_in[11];
    const float* W1    = (const float*)d_in[12];
    const float* b1    = (const float*)d_in[13];
    const float* vals1 = (const float*)d_in[14];
    const int*   rows1 = (const int*)d_in[15];
    const int*   cols1 = (const int*)d_in[16];
    const float* U2    = (const float*)d_in[17];
    const float* Ub2   = (const float*)d_in[18];
    const float* W2    = (const float*)d_in[19];
    const float* b2    = (const float*)d_in[20];
    const float* vals2 = (const float*)d_in[21];
    const int*   rows2 = (const int*)d_in[22];
    const int*   cols2 = (const int*)d_in[23];

    float* ws = (float*)d_ws;
    float* fbuf0 = ws;                      // 131072 (fc output)
    float* fWq   = fbuf0 + 131072;          // 262144 (frag buffer storage)
    float* UbW   = fWq   + 262144;          // 131072
    float* up    = UbW   + 131072;          // 1048576
    int*   cnt   = (int*)(up + 1048576);    // 21760 (+pad to 8B align)
    int2*  ecv   = (int2*)(cnt + 21764);    // 21504*128 int2 = 22 MB

    ushort* Fq16 = (ushort*)fWq;
    float* out = (float*)d_out;

    // 1: fc + cnt-zero
    hipLaunchKernelGGL(k_prep, dim3(596), dim3(TPB), 0, stream, lat, fcW, fcb, fbuf0, cnt);
    // 2: bucket build (packed) + fold0 + UbW0
    hipLaunchKernelGGL(k_build, dim3(2112), dim3(TPB), 0, stream,
                       rows0, cols0, vals0, rows1, cols1, vals1, rows2, cols2, vals2,
                       cnt, ecv, fbuf0, W0, Ub0, Fq16, UbW);
    // 3: layer-0 GEMM: M=1024 K=256 NTOT=512, CF=8 RF=1 -> grid (64,4)
    hipLaunchKernelGGL((k_gemm_ws<256, 512, 64, 8, 1>), dim3(64, 4), dim3(TPB), 0, stream,
                       U0, Fq16, UbW, up);
    // 4: fused gather0 + fold1  (NPB=1: 1024 blocks + 512 tail)
    hipLaunchKernelGGL((k_gf<1, 512, 64, 32, 256, 1024, 1024, 0, 4096>),
                       dim3(1536), dim3(TPB), 0, stream,
                       up, cnt, ecv, b0, W1, Ub1, Fq16, UbW);
    // 5: layer-1 GEMM: M=4096 K=1024 NTOT=256, CF=8 RF=1 -> grid (256,2)
    hipLaunchKernelGGL((k_gemm_ws<1024, 256, 32, 8, 1>), dim3(256, 2), dim3(TPB), 0, stream,
                       U1, Fq16, UbW, up);
    // 6: fused gather1 + fold2  (NPB=8: 512 blocks + 192 tail)
    hipLaunchKernelGGL((k_gf<8, 256, 32, 3, 32, 4096, 4096, 1024, 16384>),
                       dim3(704), dim3(TPB), 0, stream,
                       up, cnt, ecv, b1, W2, Ub2, Fq16, UbW);
    // 7: layer-2 GEMM: M=16384 K=4096 NTOT=24(pad32), CF=2 RF=2 -> grid (512,1)
    hipLaunchKernelGGL((k_gemm_ws<4096, 24, 3, 2, 2>), dim3(512, 1), dim3(TPB), 0, stream,
                       U2, Fq16, UbW, up);
    // 8: final gather + relu + bias + transpose
    hipLaunchKernelGGL((k_gather_out<24, 3, 16384, 5120>), dim3(384), dim3(TPB), 0, stream,
                       up, cnt, ecv, b2, out);
}